// Round 7
// baseline (204.448 us; speedup 1.0000x reference)
//
#include <hip/hip_runtime.h>
#include <math.h>

// IlluminationModel, MFMA split-bf16 pipeline for MI355X (gfx950), round 7.
// B=16384, N=1024, K=64. Output: zncc (B*N) then pred_depths (B), f32.
//
// GEMMs run as bf16 hi/lo split (v = hi + lo) on mfma_f32_16x16x32_bf16:
//   A*B = Ah*Bh + Ah*Bl + Al*Bh  (error ~2^-18 relative, ~f32-equivalent).
//
// Round-7: latency attack. 512-thr blocks (8 waves, 16 rows) halve per-wave
// serial chain at same 16 waves/CU; irf gathers become contiguous scalar
// loads from a duplicated global irf2 table (L1-hot, no LDS, no barrier);
// rolling prefetch (noise/irf/B-frags); GEMM2 MFMA chain split 2x3.
//
// ws layout (floats):
//   [0,2064)   irf2: irf_input duplicated (t, t+1024, t<16 also t+2048)
//   [2080]     S
//   [2084...)  u16 cmatH[64K], cmatL[64K], corrTH[64K], corrTL[64K]

#define NT 1024

typedef unsigned short u16;
typedef short bf16x8 __attribute__((ext_vector_type(8)));
typedef float f32x4 __attribute__((ext_vector_type(4)));

__device__ __forceinline__ u16 f2bf(float f) {          // round-to-nearest-even
  unsigned u = __float_as_uint(f);
  u = u + 0x7FFFu + ((u >> 16) & 1u);
  return (u16)(u >> 16);
}
__device__ __forceinline__ float bf2f(u16 h) {
  return __uint_as_float(((unsigned)h) << 16);
}

// Single-block prelude: gaussian IRF -> normalize/roll -> relu(x) -> circular
// conv (|d|<=96; dropped terms < e^-46) -> duplicated irf2 table + sum S.
__global__ __launch_bounds__(1024) void prelude(const float* __restrict__ learn,
                                                float* __restrict__ irf2,
                                                float* __restrict__ S) {
  __shared__ float red[NT];
  __shared__ float irf_l[NT];
  __shared__ float x_l[NT];
  int t = threadIdx.x;
  float d = ((float)t - 511.0f) / 10.0f;               // mu=511, sigma=10
  float g = expf(-0.5f * d * d);
  red[t] = g;
  __syncthreads();
  for (int s = 512; s > 0; s >>= 1) {
    if (t < s) red[t] += red[t + s];
    __syncthreads();
  }
  float gsum = red[0];
  irf_l[(t - 511) & (NT - 1)] = g / gsum;              // roll by -mu
  x_l[t] = fmaxf(learn[t], 0.0f);
  __syncthreads();
  float acc = 0.0f;
  for (int dd = -96; dd <= 96; ++dd)
    acc += irf_l[dd & (NT - 1)] * x_l[(t - dd) & (NT - 1)];
  irf2[t] = acc;
  irf2[t + 1024] = acc;
  if (t < 16) irf2[t + 2048] = acc;                    // pad for +7 overread
  red[t] = acc;
  __syncthreads();
  for (int s = 512; s > 0; s >>= 1) {
    if (t < s) red[t] += red[t + s];
    __syncthreads();
  }
  if (t == 0) S[0] = red[0];
}

// corr_init: corr_norm (zero-mean/L2 over k, stored transposed [n][k] bf16
// planes) + cmat -> bf16 hi/lo plane conversion.
__global__ __launch_bounds__(256) void corr_init(const float* __restrict__ cmat,
                                                 u16* __restrict__ corrTH,
                                                 u16* __restrict__ corrTL,
                                                 u16* __restrict__ cmatH,
                                                 u16* __restrict__ cmatL) {
  int tid = threadIdx.x;
  {
    int idx = blockIdx.x * 256 + tid;                  // 65536 elems coalesced
    float v = cmat[idx];
    u16 h = f2bf(v);
    cmatH[idx] = h;
    cmatL[idx] = f2bf(v - bf2f(h));
  }
  int lane = tid & 63;
  int wv = tid >> 6;
  int n = blockIdx.x * 4 + wv;
  float w = cmat[lane * NT + n];
  float s = w;
#pragma unroll
  for (int off = 32; off > 0; off >>= 1) s += __shfl_xor(s, off);
  float mean = s * (1.0f / 64.0f);
  float dd = w - mean;
  float q = dd * dd;
#pragma unroll
  for (int off = 32; off > 0; off >>= 1) q += __shfl_xor(q, off);
  float val = dd / (sqrtf(q) + 1e-8f);
  u16 h = f2bf(val);
  corrTH[n * 64 + lane] = h;
  corrTL[n * 64 + lane] = f2bf(val - bf2f(h));
}

// Fused main: 16 batch rows per block, 8 waves (512 thr), grid = B/16 = 1024.
__global__ __launch_bounds__(512, 4) void fused_main(const int* __restrict__ bins,
                                                     const float* __restrict__ photon,
                                                     const float* __restrict__ sbrs,
                                                     const float* __restrict__ noise,
                                                     const float* __restrict__ irf2,
                                                     const float* __restrict__ Sp,
                                                     const u16* __restrict__ cmatH,
                                                     const u16* __restrict__ cmatL,
                                                     const u16* __restrict__ corrTH,
                                                     const u16* __restrict__ corrTL,
                                                     float* __restrict__ zncc,
                                                     float* __restrict__ pred) {
  __shared__ float part[8][16][68];                // 34.8KB [wave][batch r][k]
  __shared__ u16 inormH[16 * 64];                  // 2KB, swizzled
  __shared__ u16 inormL[16 * 64];
  __shared__ float red_m[8][16];
  __shared__ float red_e[8][16];
  __shared__ float red_n[8][16];

  int tid = threadIdx.x;
  int lane = tid & 63, w = tid >> 6;               // w in 0..7
  int row = lane & 15, kg = lane >> 4;             // MFMA fragment coords
  long b0 = (long)blockIdx.x * 16;
  long b = b0 + row;

  int shift = bins[b] & (NT - 1);
  float ph = photon[b];
  float sb = sbrs[b];
  float S = Sp[0];
  float scal = ph / S;
  float amb = ph / sb * (1.0f / 1024.0f);

  // wave w owns cols [128w, 128w+128); lane's 8-col slice at 8kg + 32s
  const float* nrow = noise + b * NT + w * 128 + 8 * kg;
  const float* ir = irf2 + (w * 128 + 8 * kg) - shift + 1024;  // contiguous, L1-hot

  // ---- GEMM1 + generation fused, rolling prefetch ----
  f32x4 acc[4];
#pragma unroll
  for (int t = 0; t < 4; ++t) acc[t] = (f32x4){0.f, 0.f, 0.f, 0.f};

  float4 nza = *reinterpret_cast<const float4*>(nrow);
  float4 nzb = *reinterpret_cast<const float4*>(nrow + 4);
  float iva[8];
#pragma unroll
  for (int e = 0; e < 8; ++e) iva[e] = ir[e];

#pragma unroll
  for (int s = 0; s < 4; ++s) {
    // prefetch next iteration's noise + irf
    float4 nza_n, nzb_n;
    float ivn[8];
    if (s < 3) {
      nza_n = *reinterpret_cast<const float4*>(nrow + 32 * (s + 1));
      nzb_n = *reinterpret_cast<const float4*>(nrow + 32 * (s + 1) + 4);
#pragma unroll
      for (int e = 0; e < 8; ++e) ivn[e] = ir[32 * (s + 1) + e];
    }
    int cabs = w * 128 + 8 * kg + 32 * s;
    // issue all 8 B-frag loads before generation (gen VALU covers latency)
    bf16x8 bh[4], bl[4];
#pragma unroll
    for (int t = 0; t < 4; ++t) {
      bh[t] = *reinterpret_cast<const bf16x8*>(cmatH + (size_t)(16 * t + row) * NT + cabs);
      bl[t] = *reinterpret_cast<const bf16x8*>(cmatL + (size_t)(16 * t + row) * NT + cabs);
    }
    // generation
    float nzv[8] = {nza.x, nza.y, nza.z, nza.w, nzb.x, nzb.y, nzb.z, nzb.w};
    bf16x8 ah, al;
#pragma unroll
    for (int e = 0; e < 8; ++e) {
      float sc = fmaf(iva[e], scal, amb);
      float v = fmaf(sqrtf(sc), nzv[e], sc);
      u16 h = f2bf(v);
      ah[e] = (short)h;
      al[e] = (short)f2bf(v - bf2f(h));
    }
#pragma unroll
    for (int t = 0; t < 4; ++t) {
      acc[t] = __builtin_amdgcn_mfma_f32_16x16x32_bf16(al, bh[t], acc[t], 0, 0, 0);
      acc[t] = __builtin_amdgcn_mfma_f32_16x16x32_bf16(ah, bl[t], acc[t], 0, 0, 0);
      acc[t] = __builtin_amdgcn_mfma_f32_16x16x32_bf16(ah, bh[t], acc[t], 0, 0, 0);
    }
    nza = nza_n; nzb = nzb_n;
#pragma unroll
    for (int e = 0; e < 8; ++e) iva[e] = ivn[e];
  }
#pragma unroll
  for (int t = 0; t < 4; ++t)
#pragma unroll
    for (int q = 0; q < 4; ++q) part[w][4 * kg + q][16 * t + row] = acc[t][q];
  __syncthreads();

  // ---- cross-wave reduce + zero-norm over k -> inorm planes ----
#pragma unroll
  for (int rr = 0; rr < 2; ++rr) {
    int r = w * 2 + rr;
    float v = part[0][r][lane] + part[1][r][lane] + part[2][r][lane] + part[3][r][lane] +
              part[4][r][lane] + part[5][r][lane] + part[6][r][lane] + part[7][r][lane];
    float s = v;
#pragma unroll
    for (int off = 32; off > 0; off >>= 1) s += __shfl_xor(s, off);
    float mean = s * (1.0f / 64.0f);
    float dd = v - mean;
    float q = dd * dd;
#pragma unroll
    for (int off = 32; off > 0; off >>= 1) q += __shfl_xor(q, off);
    float val = dd / (sqrtf(q) + 1e-8f);
    u16 h = f2bf(val);
    u16 lo = f2bf(val - bf2f(h));
    int boff = (r * 128 + lane * 2) ^ ((r & 7) << 4);
    *reinterpret_cast<u16*>(reinterpret_cast<char*>(inormH) + boff) = h;
    *reinterpret_cast<u16*>(reinterpret_cast<char*>(inormL) + boff) = lo;
  }
  __syncthreads();

  // ---- GEMM2: wave w owns n in [128w, 128w+128), 8 tiles of 16 ----
  int swz = (row & 7) << 4;
  int a0 = (row * 128 + 16 * kg) ^ swz;            // kc = 0
  int a1 = (row * 128 + 64 + 16 * kg) ^ swz;       // kc = 32
  bf16x8 a2h0 = *reinterpret_cast<const bf16x8*>(reinterpret_cast<const char*>(inormH) + a0);
  bf16x8 a2h1 = *reinterpret_cast<const bf16x8*>(reinterpret_cast<const char*>(inormH) + a1);
  bf16x8 a2l0 = *reinterpret_cast<const bf16x8*>(reinterpret_cast<const char*>(inormL) + a0);
  bf16x8 a2l1 = *reinterpret_cast<const bf16x8*>(reinterpret_cast<const char*>(inormL) + a1);

  const u16* pH = corrTH + (size_t)(128 * w + row) * 64 + 8 * kg;  // j stride: 1024 u16
  const u16* pL = corrTL + (size_t)(128 * w + row) * 64 + 8 * kg;

  f32x4 acc2[8];
  f32x4 mx = {-INFINITY, -INFINITY, -INFINITY, -INFINITY};
  bf16x8 b0h = *reinterpret_cast<const bf16x8*>(pH);
  bf16x8 b1h = *reinterpret_cast<const bf16x8*>(pH + 32);
  bf16x8 b0l = *reinterpret_cast<const bf16x8*>(pL);
  bf16x8 b1l = *reinterpret_cast<const bf16x8*>(pL + 32);
#pragma unroll
  for (int j = 0; j < 8; ++j) {
    bf16x8 nb0h, nb1h, nb0l, nb1l;
    if (j < 7) {                                   // prefetch next tile's B
      nb0h = *reinterpret_cast<const bf16x8*>(pH + (j + 1) * 1024);
      nb1h = *reinterpret_cast<const bf16x8*>(pH + (j + 1) * 1024 + 32);
      nb0l = *reinterpret_cast<const bf16x8*>(pL + (j + 1) * 1024);
      nb1l = *reinterpret_cast<const bf16x8*>(pL + (j + 1) * 1024 + 32);
    }
    f32x4 z1 = {0.f, 0.f, 0.f, 0.f}, z2 = z1;      // two independent 3-chains
    z1 = __builtin_amdgcn_mfma_f32_16x16x32_bf16(a2l0, b0h, z1, 0, 0, 0);
    z2 = __builtin_amdgcn_mfma_f32_16x16x32_bf16(a2h0, b0l, z2, 0, 0, 0);
    z1 = __builtin_amdgcn_mfma_f32_16x16x32_bf16(a2h0, b0h, z1, 0, 0, 0);
    z2 = __builtin_amdgcn_mfma_f32_16x16x32_bf16(a2l1, b1h, z2, 0, 0, 0);
    z1 = __builtin_amdgcn_mfma_f32_16x16x32_bf16(a2h1, b1l, z1, 0, 0, 0);
    z2 = __builtin_amdgcn_mfma_f32_16x16x32_bf16(a2h1, b1h, z2, 0, 0, 0);
    f32x4 z = z1 + z2;
    acc2[j] = z;
    int n0 = 128 * w + 16 * j;
#pragma unroll
    for (int q = 0; q < 4; ++q) {
      zncc[(b0 + 4 * kg + q) * NT + n0 + row] = z[q];
      mx[q] = fmaxf(mx[q], z[q]);
    }
    b0h = nb0h; b1h = nb1h; b0l = nb0l; b1l = nb1l;
  }

  // row-max: reduce within 16-lane group, then across 8 waves
#pragma unroll
  for (int q = 0; q < 4; ++q) {
#pragma unroll
    for (int off = 1; off < 16; off <<= 1) mx[q] = fmaxf(mx[q], __shfl_xor(mx[q], off));
  }
  if (row == 0) {
#pragma unroll
    for (int q = 0; q < 4; ++q) red_m[w][4 * kg + q] = mx[q];
  }
  __syncthreads();
  f32x4 rm;
#pragma unroll
  for (int q = 0; q < 4; ++q) {
    float m = red_m[0][4 * kg + q];
#pragma unroll
    for (int p = 1; p < 8; ++p) m = fmaxf(m, red_m[p][4 * kg + q]);
    rm[q] = m;
  }

  // exp pass over register-resident zncc tile
  f32x4 es = {0.f, 0.f, 0.f, 0.f}, ns = es;
#pragma unroll
  for (int j = 0; j < 8; ++j) {
    float nf = (float)(128 * w + 16 * j + row);
#pragma unroll
    for (int q = 0; q < 4; ++q) {
      float e = __expf(100.0f * (acc2[j][q] - rm[q]));
      es[q] += e;
      ns[q] = fmaf(nf, e, ns[q]);
    }
  }
#pragma unroll
  for (int q = 0; q < 4; ++q) {
#pragma unroll
    for (int off = 1; off < 16; off <<= 1) {
      es[q] += __shfl_xor(es[q], off);
      ns[q] += __shfl_xor(ns[q], off);
    }
  }
  if (row == 0) {
#pragma unroll
    for (int q = 0; q < 4; ++q) { red_e[w][4 * kg + q] = es[q]; red_n[w][4 * kg + q] = ns[q]; }
  }
  __syncthreads();
  if (tid < 16) {
    float e = 0.f, n = 0.f;
#pragma unroll
    for (int p = 0; p < 8; ++p) { e += red_e[p][tid]; n += red_n[p][tid]; }
    pred[b0 + tid] = n / e;
  }
}

extern "C" void kernel_launch(void* const* d_in, const int* in_sizes, int n_in,
                              void* d_out, int out_size, void* d_ws, size_t ws_size,
                              hipStream_t stream) {
  const int*   bins   = (const int*)d_in[0];
  const float* photon = (const float*)d_in[1];
  const float* sbrs   = (const float*)d_in[2];
  const float* learn  = (const float*)d_in[3];
  const float* cmat   = (const float*)d_in[4];
  const float* noise  = (const float*)d_in[5];
  float* out = (float*)d_out;
  float* wsf = (float*)d_ws;

  float* irf2  = wsf;                      // 2064 f32 (duplicated + pad)
  float* Sslot = wsf + 2080;               // 1 f32
  u16* cmatH  = (u16*)(wsf + 2084);        // 65536 u16 each
  u16* cmatL  = cmatH + 65536;
  u16* corrTH = cmatL + 65536;             // [n][k] transposed planes
  u16* corrTL = corrTH + 65536;

  int B = in_sizes[0];
  float* pred = out + (size_t)B * NT;

  hipLaunchKernelGGL(prelude, dim3(1), dim3(1024), 0, stream, learn, irf2, Sslot);
  hipLaunchKernelGGL(corr_init, dim3(256), dim3(256), 0, stream,
                     cmat, corrTH, corrTL, cmatH, cmatL);
  hipLaunchKernelGGL(fused_main, dim3(B / 16), dim3(512), 0, stream,
                     bins, photon, sbrs, noise, irf2, Sslot,
                     cmatH, cmatL, corrTH, corrTL, out, pred);
}